// Round 3
// baseline (198.811 us; speedup 1.0000x reference)
//
#include <hip/hip_runtime.h>
#include <stdint.h>

// ---------------------------------------------------------------------------
// MultiheadMaskedAttention (B=2, S=2048, H=1024, 16 heads x d=64)
// R12: R11 with the partial-merge scratch layout fixed for 32-row waves.
// R11's bug: sL[w*16+ql] / sO[w*2048 + {0,1024} + ql*64 + l31] were sized
// for 16 q-locals; ql is 0..31 -> wave 0/1 and O0/O1 regions overlapped
// (wrong denominators for half of group-B's rows, absmax 0.0428).
// Fixed layout: sO[w*2048 + ql*64 + half*32 + l31] (4096 floats, exactly
// Vs), sL[w*32 + ql] (64 floats, in Ks).
// Structure (from R10/R11):
//  - 32-row waves on 32x32x16 MFMA halve LDS fragment reads per q-row.
//  - P via per-wave LDS [32 q][72 s] (R9-proven round trip).
//  - Balance: block = 4 waves over groups (p, 31-p). Waves 0-1 finish group
//    p at t==p, write it, then take ms=1 of group 31-p's remaining tiles
//    while waves 2-3 take ms=0; merged via LDS scratch at the end.
// KV staging/swizzle/dbuf as R9. GEMMs / prep unchanged.
// ---------------------------------------------------------------------------

typedef __bf16 bf16;
typedef __attribute__((ext_vector_type(8))) __bf16 bf16x8;
typedef __attribute__((ext_vector_type(4))) __bf16 bf16x4;
typedef __attribute__((ext_vector_type(4))) float floatx4;
typedef __attribute__((ext_vector_type(16))) float floatx16;

#define SCL 0.18033688011112042f  // (1/sqrt(64)) * log2(e)

__device__ __forceinline__ floatx4 mfma_bf16(bf16x8 a, bf16x8 b, floatx4 c) {
  return __builtin_amdgcn_mfma_f32_16x16x32_bf16(a, b, c, 0, 0, 0);
}

// 32x32x16: A lane l holds m=l&31, k=(l>>5)*8+j ; B: n=l&31, k=(l>>5)*8+j ;
// D: n=lane&31, m=(reg&3)+8*(reg>>2)+4*(lane>>5)  [verified m74/m101]
__device__ __forceinline__ floatx16 mfma32(bf16x8 a, bf16x8 b, floatx16 c) {
  return __builtin_amdgcn_mfma_f32_32x32x16_bf16(a, b, c, 0, 0, 0);
}

__device__ __forceinline__ void cp_g2l_16(const bf16* g, bf16* l) {
  // async global->LDS, 16B/lane; LDS dest = wave-uniform base + lane*16
  __builtin_amdgcn_global_load_lds(
      (const __attribute__((address_space(1))) void*)g,
      (__attribute__((address_space(3))) void*)l, 16, 0, 0);
}

__device__ __forceinline__ floatx16 zero16() {
  floatx16 z;
#pragma unroll
  for (int i = 0; i < 16; ++i) z[i] = 0.f;
  return z;
}

// ---- merged prep: cast x -> bf16 ; cast+transpose w_qkv, w_o ----
__global__ __launch_bounds__(256) void prep_kernel(
    const float* __restrict__ x, bf16* __restrict__ xb,
    const float* __restrict__ w_qkv, bf16* __restrict__ wqkvt,
    const float* __restrict__ w_o, bf16* __restrict__ wot) {
  const int b = blockIdx.x;
  const int tid = threadIdx.x;
  if (b < 4096) {
    const int i = (b * 256 + tid) * 4;
    floatx4 v = *(const floatx4*)(x + i);
    bf16x4 o;
    o[0] = (bf16)v[0]; o[1] = (bf16)v[1]; o[2] = (bf16)v[2]; o[3] = (bf16)v[3];
    *(bf16x4*)(xb + i) = o;
    return;
  }
  __shared__ float tile[32][33];
  const float* W; bf16* Wt; int K, N, n0, k0;
  if (b < 7168) {
    const int bb = b - 4096;
    W = w_qkv; Wt = wqkvt; K = 1024; N = 3072;
    n0 = (bb % 96) * 32; k0 = (bb / 96) * 32;
  } else {
    const int bb = b - 7168;
    W = w_o; Wt = wot; K = 1024; N = 1024;
    n0 = (bb & 31) * 32; k0 = (bb >> 5) * 32;
  }
  const int tx = tid & 31, ty = tid >> 5;
  for (int i = 0; i < 4; ++i)
    tile[ty + 8 * i][tx] = W[(size_t)(k0 + ty + 8 * i) * N + n0 + tx];
  __syncthreads();
  for (int i = 0; i < 4; ++i)
    Wt[(size_t)(n0 + ty + 8 * i) * K + k0 + tx] = (bf16)tile[tx][ty + 8 * i];
}

// ---- GEMM: C = A(M x K bf16 rm) * Bt(N x K bf16 rm)^T + bias ----
template <int MODE, int MI>
__global__ __launch_bounds__(256, 3) void gemm_bt_kernel(
    const bf16* __restrict__ A, const bf16* __restrict__ Bt,
    const float* __restrict__ bias, float* __restrict__ outF,
    bf16* __restrict__ qb, bf16* __restrict__ kb, bf16* __restrict__ vtb,
    int N, int K) {
  constexpr int BM = MI * 32;
  __shared__ bf16 As[BM * 32];
  __shared__ bf16 Bs[128 * 32];
  const int tid = threadIdx.x;
  const int w = tid >> 6, lane = tid & 63;
  const int l16 = lane & 15, quad = lane >> 4;
  const int m0 = blockIdx.y * BM, n0 = blockIdx.x * 128;
  const int wm = (w & 1) * (BM / 2), wn = (w >> 1) * 64;

  const int arow = w * (BM / 4) + (lane >> 2);
  const int acol = (lane & 3) * 8;
  const bf16* Ag = A + (size_t)(m0 + arow) * K + acol;
  bf16* Al = As + arow * 32 + acol;
  const int brow = w * 32 + (lane >> 2);
  const bf16* Bg = Bt + (size_t)(n0 + brow) * K + acol;
  bf16* Bl = Bs + brow * 32 + acol;

  floatx4 acc[MI][4];
#pragma unroll
  for (int i = 0; i < MI; ++i)
#pragma unroll
    for (int j = 0; j < 4; ++j) acc[i][j] = (floatx4){0.f, 0.f, 0.f, 0.f};

  for (int k0 = 0; k0 < K; k0 += 32) {
    __syncthreads();
    cp_g2l_16(Ag + k0, Al);
    if (MI == 4) cp_g2l_16(Ag + (size_t)16 * K + k0, Al + 16 * 32);
    cp_g2l_16(Bg + k0, Bl);
    cp_g2l_16(Bg + (size_t)16 * K + k0, Bl + 16 * 32);
    __syncthreads();
    bf16x8 af[MI], bfr[4];
#pragma unroll
    for (int i = 0; i < MI; ++i)
      af[i] = *(const bf16x8*)(&As[(wm + i * 16 + l16) * 32 + quad * 8]);
#pragma unroll
    for (int j = 0; j < 4; ++j)
      bfr[j] = *(const bf16x8*)(&Bs[(wn + j * 16 + l16) * 32 + quad * 8]);
#pragma unroll
    for (int i = 0; i < MI; ++i)
#pragma unroll
      for (int j = 0; j < 4; ++j)
        acc[i][j] = mfma_bf16(af[i], bfr[j], acc[i][j]);
  }

#pragma unroll
  for (int i = 0; i < MI; ++i)
#pragma unroll
    for (int j = 0; j < 4; ++j) {
      const int nn = n0 + wn + j * 16 + l16;
      const float bv = bias[nn];
      const int mbase = m0 + wm + i * 16 + quad * 4;
      if (MODE == 1) {
#pragma unroll
        for (int r = 0; r < 4; ++r)
          outF[(size_t)(mbase + r) * N + nn] = acc[i][j][r] + bv;
      } else {
        const int which = nn >> 10;  // uniform per block
        const int rem = nn & 1023;
        const int h = rem >> 6, d = rem & 63;
        const int b = mbase >> 11, s = mbase & 2047;
        const size_t bh = (size_t)(b * 16 + h);
        if (which == 2) {
          bf16x4 pk;
#pragma unroll
          for (int r = 0; r < 4; ++r) pk[r] = (bf16)(acc[i][j][r] + bv);
          *(bf16x4*)(vtb + (bh * 64 + d) * 2048 + s) = pk;
        } else if (which == 0) {
#pragma unroll
          for (int r = 0; r < 4; ++r)
            qb[(bh * 2048 + s + r) * 64 + d] = (bf16)((acc[i][j][r] + bv) * SCL);
        } else {
#pragma unroll
          for (int r = 0; r < 4; ++r)
            kb[(bh * 2048 + s + r) * 64 + d] = (bf16)(acc[i][j][r] + bv);
        }
      }
    }
}

// ---- Flash attention, causal: 32-row waves, LDS P round-trip, balance. --
// 512 blocks x 256 threads. Block p covers groups p (waves 0-1) and 31-p
// (waves 2-3) of one head. Waves 0-1 finish group p at t==p, write it, then
// accumulate the ms=1 (s 32..63) half of group 31-p's tiles into fresh
// accumulators while waves 2-3 take ms=0; merged via LDS at the end.
__global__ __launch_bounds__(256, 3) void attn_kernel(
    const bf16* __restrict__ Qb, const bf16* __restrict__ Kb,
    const bf16* __restrict__ Vtb, bf16* __restrict__ attnb) {
  __shared__ bf16 Ks[2][4096];   // [buf][64 s-rows x 64 d] swizzled chunks
  __shared__ bf16 Vs[2][4096];   // [buf][64 d-rows x 64 s] swizzled chunks
  __shared__ bf16 Ps[4 * 2304];  // per-wave P: 32 q-rows x 72 (s-major)
  const int bid = blockIdx.x;
  const int bh = (bid & 7) * 4 + ((bid >> 3) & 3);  // 4 heads per XCD
  const int p = bid >> 5;                           // pair id 0..15
  const int tid = threadIdx.x;
  const int w = tid >> 6, lane = tid & 63;
  const int l31 = lane & 31, hi = lane >> 5;
  const int b = bh >> 4, h = bh & 15;
  const bool hw = (w < 2);  // group-p waves (retire early, then help)
  const int gB = 31 - p;
  const int q0A = p * 64 + (w & 1) * 32;
  const int q0B = gB * 64 + (w & 1) * 32;
  const int nt = 32 - p;

  const bf16* Qh = Qb + (size_t)bh * 2048 * 64;
  const bf16* Kh = Kb + (size_t)bh * 2048 * 64;
  const bf16* Vh = Vtb + (size_t)bh * 64 * 2048;
  bf16* Pw = Ps + w * 2304;

  // staging: thread stages chunks {tid, tid+256} of K and of V (16B each).
  // dest chunk c: row=c>>3, slot=c&7 holds source chunk (slot-row)&7
  const int c0 = tid, c1 = tid + 256;
  const int kof0 = (c0 >> 3) * 64 + ((((c0 & 7) - (c0 >> 3)) & 7) * 8);
  const int kof1 = (c1 >> 3) * 64 + ((((c1 & 7) - (c1 >> 3)) & 7) * 8);
  const int vof0 = (c0 >> 3) * 2048 + ((((c0 & 7) - (c0 >> 3)) & 7) * 8);
  const int vof1 = (c1 >> 3) * 2048 + ((((c1 & 7) - (c1 >> 3)) & 7) * 8);

  // Q B-frags for the current strip: n=q=q0+l31, k=d=kd*16+hi*8+j
  int q0 = hw ? q0A : q0B;
  int wdiag = hw ? p : gB;
  bf16x8 qf[4];
  {
    const bf16* Qr = Qh + (size_t)(q0 + l31) * 64 + hi * 8;
#pragma unroll
    for (int kd = 0; kd < 4; ++kd) qf[kd] = *(const bf16x8*)(Qr + kd * 16);
  }
  bf16x8 ones;
#pragma unroll
  for (int j = 0; j < 8; ++j) ones[j] = (bf16)1.0f;

  floatx16 O0 = zero16(), O1 = zero16(), Ol = zero16();

  // one ms half: kf reads + 4 chained QK MFMAs -> mask/exp2 -> 4 b64 writes
  // into Pw. C-frag reg r holds s_local = ms*32 + (r&3) + 8*(r>>2) + 4*hi,
  // q = q0+l31; quad a=(r>>2) packs 4 consecutive s.
  auto do_ms = [&](int ms, const bf16* KsC, int t, bool diag, int q0c) {
    floatx16 sf = zero16();
    const int row = ms * 32 + l31;
#pragma unroll
    for (int kd = 0; kd < 4; ++kd) {
      bf16x8 kf = *(const bf16x8*)(
          &KsC[row * 64 + (((kd * 2 + hi) + row) & 7) * 8]);
      sf = mfma32(kf, qf[kd], sf);
    }
#pragma unroll
    for (int a = 0; a < 4; ++a) {
      bf16x4 pk;
#pragma unroll
      for (int bq = 0; bq < 4; ++bq) {
        float s = sf[a * 4 + bq];
        if (diag) {
          const int kc = t * 64 + ms * 32 + bq + 8 * a + 4 * hi;
          s = (kc <= q0c + l31) ? s : -1e30f;
        }
        pk[bq] = (bf16)__builtin_amdgcn_exp2f(s);
      }
      *(bf16x4*)(&Pw[l31 * 72 + ms * 32 + 8 * a + 4 * hi]) = pk;
    }
  };

  // P A-frag for k-slot ks: m=q=l31, k = hi*8+j within slot (b128 read)
  auto ld_p = [&](int ks) {
    return *(const bf16x8*)(&Pw[l31 * 72 + ks * 16 + hi * 8]);
  };

  // PV for one k-slot ks: O[q][d] += P*V over s=ks*16..+15 ; l += P*1
  auto pv_ks = [&](const bf16* VsC, bf16x8 pfk, int ks) {
    const int r0 = l31, r1 = 32 + l31;
    bf16x8 v0 = *(const bf16x8*)(
        &VsC[r0 * 64 + (((ks * 2 + hi) + r0) & 7) * 8]);
    O0 = mfma32(pfk, v0, O0);
    bf16x8 v1 = *(const bf16x8*)(
        &VsC[r1 * 64 + (((ks * 2 + hi) + r1) & 7) * 8]);
    O1 = mfma32(pfk, v1, O1);
    Ol = mfma32(pfk, ones, Ol);
  };

  // epilogue write: O rows q=qb+(r&3)+8*(r>>2)+4*hi, cols d={l31, 32+l31}
  auto outW = [&](int qb) {
#pragma unroll
    for (int r = 0; r < 16; ++r) {
      const int q = qb + (r & 3) + 8 * (r >> 2) + 4 * hi;
      const float inv = 1.f / Ol[r];
      bf16* dst = attnb + ((size_t)(b * 2048 + q)) * 1024 + h * 64;
      dst[l31] = (bf16)(O0[r] * inv);
      dst[32 + l31] = (bf16)(O1[r] * inv);
    }
  };

  // prologue: stage tile 0 into buffer 0
  cp_g2l_16(Kh + kof0, &Ks[0][c0 * 8]);
  cp_g2l_16(Kh + kof1, &Ks[0][c1 * 8]);
  cp_g2l_16(Vh + vof0, &Vs[0][c0 * 8]);
  cp_g2l_16(Vh + vof1, &Vs[0][c1 * 8]);

  int cur = 0;
  for (int t = 0; t < nt; ++t, cur ^= 1) {
    __syncthreads();  // buf[cur] staged; all waves done with buf[cur^1]
    if (t + 1 < nt) {  // prefetch t+1 into the other buffer
      const int nb = cur ^ 1;
      cp_g2l_16(Kh + (size_t)(t + 1) * 4096 + kof0, &Ks[nb][c0 * 8]);
      cp_g2l_16(Kh + (size_t)(t + 1) * 4096 + kof1, &Ks[nb][c1 * 8]);
      cp_g2l_16(Vh + (size_t)(t + 1) * 64 + vof0, &Vs[nb][c0 * 8]);
      cp_g2l_16(Vh + (size_t)(t + 1) * 64 + vof1, &Vs[nb][c1 * 8]);
    }
    const bf16* KsC = Ks[cur];
    const bf16* VsC = Vs[cur];
    const bool full = (t <= p);
    const bool diag = (t == wdiag);

    if (full) {  // own strip, all 64 s
      do_ms(0, KsC, t, diag, q0);
      do_ms(1, KsC, t, diag, q0);
      bf16x8 p0 = ld_p(0), p1 = ld_p(1), p2 = ld_p(2), p3 = ld_p(3);
      pv_ks(VsC, p0, 0); pv_ks(VsC, p1, 1);
      pv_ks(VsC, p2, 2); pv_ks(VsC, p3, 3);
    } else if (hw) {  // helper: s-upper half of partner strip
      do_ms(1, KsC, t, diag, q0);
      bf16x8 p2 = ld_p(2), p3 = ld_p(3);
      pv_ks(VsC, p2, 2); pv_ks(VsC, p3, 3);
    } else {  // owner: s-lower half
      do_ms(0, KsC, t, diag, q0);
      bf16x8 p0 = ld_p(0), p1 = ld_p(1);
      pv_ks(VsC, p0, 0); pv_ks(VsC, p1, 1);
    }

    if (hw && t == p) {  // group p complete: retire, switch to group 31-p
      outW(q0A);
      O0 = zero16(); O1 = zero16(); Ol = zero16();
      q0 = q0B; wdiag = gB;
      const bf16* Qr = Qh + (size_t)(q0B + l31) * 64 + hi * 8;
#pragma unroll
      for (int kd = 0; kd < 4; ++kd) qf[kd] = *(const bf16x8*)(Qr + kd * 16);
    }
  }

  // merge partials for group 31-p: waves 0-1 -> LDS, waves 2-3 add + write.
  // sO: [w][ql 0..31][d 0..63] = w*2048 + ql*64 + half*32 + l31 (4096 floats
  // = exactly Vs). sL: [w][ql 0..31] (64 floats, in Ks).
  __syncthreads();
  float* sO = (float*)(&Vs[0][0]);
  float* sL = (float*)(&Ks[0][0]);
  if (hw) {
#pragma unroll
    for (int r = 0; r < 16; ++r) {
      const int ql = (r & 3) + 8 * (r >> 2) + 4 * hi;
      sO[w * 2048 + ql * 64 + l31] = O0[r];
      sO[w * 2048 + ql * 64 + 32 + l31] = O1[r];
      if (l31 == 0) sL[w * 32 + ql] = Ol[r];
    }
  }
  __syncthreads();
  if (!hw) {
    const int pw = w - 2;
#pragma unroll
    for (int r = 0; r < 16; ++r) {
      const int ql = (r & 3) + 8 * (r >> 2) + 4 * hi;
      O0[r] += sO[pw * 2048 + ql * 64 + l31];
      O1[r] += sO[pw * 2048 + ql * 64 + 32 + l31];
      Ol[r] += sL[pw * 32 + ql];
    }
    outW(q0B);
  }
}

// ---------------------------------------------------------------------------
extern "C" void kernel_launch(void* const* d_in, const int* in_sizes, int n_in,
                              void* d_out, int out_size, void* d_ws, size_t ws_size,
                              hipStream_t stream) {
  const float* x     = (const float*)d_in[0];  // (2,2048,1024)
  const float* w_qkv = (const float*)d_in[1];  // (1024,3072)
  const float* b_qkv = (const float*)d_in[2];  // (3072)
  const float* w_o   = (const float*)d_in[3];  // (1024,1024)
  const float* b_o   = (const float*)d_in[4];  // (1024)
  float* out = (float*)d_out;                  // (2,2048,1024) fp32

  char* ws = (char*)d_ws;
  bf16* xb    = (bf16*)ws; ws += (size_t)4096 * 1024 * 2;
  bf16* wqkvt = (bf16*)ws; ws += (size_t)3072 * 1024 * 2;
  bf16* wot   = (bf16*)ws; ws += (size_t)1024 * 1024 * 2;
  bf16* qb    = (bf16*)ws; ws += (size_t)32 * 2048 * 64 * 2;
  bf16* kb    = (bf16*)ws; ws += (size_t)32 * 2048 * 64 * 2;
  bf16* vtb   = (bf16*)ws; ws += (size_t)32 * 2048 * 64 * 2;  // (bh,64,S)
  bf16* attnb = (bf16*)ws; ws += (size_t)4096 * 1024 * 2;

  prep_kernel<<<8192, 256, 0, stream>>>(x, xb, w_qkv, wqkvt, w_o, wot);
  gemm_bt_kernel<0, 4><<<dim3(24, 32), 256, 0, stream>>>(
      xb, wqkvt, b_qkv, nullptr, qb, kb, vtb, 3072, 1024);
  attn_kernel<<<512, 256, 0, stream>>>(qb, kb, vtb, attnb);
  gemm_bt_kernel<1, 2><<<dim3(8, 64), 256, 0, stream>>>(
      attnb, wot, b_o, out, nullptr, nullptr, nullptr, 1024, 1024);
}

// Round 4
// 176.417 us; speedup vs baseline: 1.1269x; 1.1269x over previous
//
#include <hip/hip_runtime.h>
#include <stdint.h>

// ---------------------------------------------------------------------------
// MultiheadMaskedAttention (B=2, S=2048, H=1024, 16 heads x d=64)
// R13: attn restructured for LDS-throughput + occupancy simultaneously.
//  - Block = one 64-row q-group, 4 waves = (strip 0/1) x (s-half ms 0/1).
//    All waves active every iteration; no pair/retire/phase logic.
//  - Grid 1024: bid -> (head = bid&31 -> fixed XCD for KV L2 locality);
//    stride-256 block columns get groups {k,31-k,8+k,23-k} = constant 66
//    tile-iters per column for cross-CU balance.
//  - LDS 32.8 KB/block (no P buffer) -> 4 blocks/CU = 16 waves/CU.
//  - P never touches LDS: T12 recipe with __builtin_amdgcn_permlane32_swap
//    (builtin, NOT R10's hand asm). Derivation vs verified layouts:
//    C-frag lane(l31,hi) reg r holds S[s=(r&3)+8(r>>2)+4hi][q=l31]; PV A-frag
//    needs P[q=l31][k=hi*8+j]. (word0,word2)=swap(pack(e0,e1),pack(e4,e5)),
//    (word1,word3)=swap(pack(e2,e3),pack(e6,e7)) per 16-s slot.
//  - Final 2-way (ms0+ms1) strip merge via dead KV LDS after the loop.
// KV staging/swizzle/dbuf as R9/R12. GEMMs / prep unchanged.
// ---------------------------------------------------------------------------

typedef __bf16 bf16;
typedef __attribute__((ext_vector_type(8))) __bf16 bf16x8;
typedef __attribute__((ext_vector_type(4))) __bf16 bf16x4;
typedef __attribute__((ext_vector_type(4))) float floatx4;
typedef __attribute__((ext_vector_type(16))) float floatx16;
typedef __attribute__((ext_vector_type(4))) unsigned int uint4v;
typedef __attribute__((ext_vector_type(2))) unsigned int uint2v;

#define SCL 0.18033688011112042f  // (1/sqrt(64)) * log2(e)

__device__ __forceinline__ floatx4 mfma_bf16(bf16x8 a, bf16x8 b, floatx4 c) {
  return __builtin_amdgcn_mfma_f32_16x16x32_bf16(a, b, c, 0, 0, 0);
}

// 32x32x16: A lane l holds m=l&31, k=(l>>5)*8+j ; B: n=l&31, k=(l>>5)*8+j ;
// D: n=lane&31, m=(reg&3)+8*(reg>>2)+4*(lane>>5)  [verified m74/m101, R12]
__device__ __forceinline__ floatx16 mfma32(bf16x8 a, bf16x8 b, floatx16 c) {
  return __builtin_amdgcn_mfma_f32_32x32x16_bf16(a, b, c, 0, 0, 0);
}

__device__ __forceinline__ void cp_g2l_16(const bf16* g, bf16* l) {
  // async global->LDS, 16B/lane; LDS dest = wave-uniform base + lane*16
  __builtin_amdgcn_global_load_lds(
      (const __attribute__((address_space(1))) void*)g,
      (__attribute__((address_space(3))) void*)l, 16, 0, 0);
}

__device__ __forceinline__ floatx16 zero16() {
  floatx16 z;
#pragma unroll
  for (int i = 0; i < 16; ++i) z[i] = 0.f;
  return z;
}

// two f32 -> one u32 of 2 bf16 (compiler emits cvt_pk; don't hand-write, m240)
__device__ __forceinline__ uint32_t pack2(float lo, float hi2) {
  union { bf16 h[2]; uint32_t u; } x;
  x.h[0] = (bf16)lo; x.h[1] = (bf16)hi2;
  return x.u;
}

// new_a = {a_lo, b_lo}, new_b = {a_hi, b_hi} across the lane<32 / lane>=32 halves
__device__ __forceinline__ uint2v permswap(uint32_t a, uint32_t b) {
  return __builtin_amdgcn_permlane32_swap(a, b, false, false);
}

__device__ __forceinline__ bf16x8 mk_pf(uint32_t w0, uint32_t w1, uint32_t w2,
                                        uint32_t w3) {
  union { uint4v u; bf16x8 v; } c;
  c.u = (uint4v){w0, w1, w2, w3};
  return c.v;
}

// ---- merged prep: cast x -> bf16 ; cast+transpose w_qkv, w_o ----
__global__ __launch_bounds__(256) void prep_kernel(
    const float* __restrict__ x, bf16* __restrict__ xb,
    const float* __restrict__ w_qkv, bf16* __restrict__ wqkvt,
    const float* __restrict__ w_o, bf16* __restrict__ wot) {
  const int b = blockIdx.x;
  const int tid = threadIdx.x;
  if (b < 4096) {
    const int i = (b * 256 + tid) * 4;
    floatx4 v = *(const floatx4*)(x + i);
    bf16x4 o;
    o[0] = (bf16)v[0]; o[1] = (bf16)v[1]; o[2] = (bf16)v[2]; o[3] = (bf16)v[3];
    *(bf16x4*)(xb + i) = o;
    return;
  }
  __shared__ float tile[32][33];
  const float* W; bf16* Wt; int K, N, n0, k0;
  if (b < 7168) {
    const int bb = b - 4096;
    W = w_qkv; Wt = wqkvt; K = 1024; N = 3072;
    n0 = (bb % 96) * 32; k0 = (bb / 96) * 32;
  } else {
    const int bb = b - 7168;
    W = w_o; Wt = wot; K = 1024; N = 1024;
    n0 = (bb & 31) * 32; k0 = (bb >> 5) * 32;
  }
  const int tx = tid & 31, ty = tid >> 5;
  for (int i = 0; i < 4; ++i)
    tile[ty + 8 * i][tx] = W[(size_t)(k0 + ty + 8 * i) * N + n0 + tx];
  __syncthreads();
  for (int i = 0; i < 4; ++i)
    Wt[(size_t)(n0 + ty + 8 * i) * K + k0 + tx] = (bf16)tile[tx][ty + 8 * i];
}

// ---- GEMM: C = A(M x K bf16 rm) * Bt(N x K bf16 rm)^T + bias ----
template <int MODE, int MI>
__global__ __launch_bounds__(256, 3) void gemm_bt_kernel(
    const bf16* __restrict__ A, const bf16* __restrict__ Bt,
    const float* __restrict__ bias, float* __restrict__ outF,
    bf16* __restrict__ qb, bf16* __restrict__ kb, bf16* __restrict__ vtb,
    int N, int K) {
  constexpr int BM = MI * 32;
  __shared__ bf16 As[BM * 32];
  __shared__ bf16 Bs[128 * 32];
  const int tid = threadIdx.x;
  const int w = tid >> 6, lane = tid & 63;
  const int l16 = lane & 15, quad = lane >> 4;
  const int m0 = blockIdx.y * BM, n0 = blockIdx.x * 128;
  const int wm = (w & 1) * (BM / 2), wn = (w >> 1) * 64;

  const int arow = w * (BM / 4) + (lane >> 2);
  const int acol = (lane & 3) * 8;
  const bf16* Ag = A + (size_t)(m0 + arow) * K + acol;
  bf16* Al = As + arow * 32 + acol;
  const int brow = w * 32 + (lane >> 2);
  const bf16* Bg = Bt + (size_t)(n0 + brow) * K + acol;
  bf16* Bl = Bs + brow * 32 + acol;

  floatx4 acc[MI][4];
#pragma unroll
  for (int i = 0; i < MI; ++i)
#pragma unroll
    for (int j = 0; j < 4; ++j) acc[i][j] = (floatx4){0.f, 0.f, 0.f, 0.f};

  for (int k0 = 0; k0 < K; k0 += 32) {
    __syncthreads();
    cp_g2l_16(Ag + k0, Al);
    if (MI == 4) cp_g2l_16(Ag + (size_t)16 * K + k0, Al + 16 * 32);
    cp_g2l_16(Bg + k0, Bl);
    cp_g2l_16(Bg + (size_t)16 * K + k0, Bl + 16 * 32);
    __syncthreads();
    bf16x8 af[MI], bfr[4];
#pragma unroll
    for (int i = 0; i < MI; ++i)
      af[i] = *(const bf16x8*)(&As[(wm + i * 16 + l16) * 32 + quad * 8]);
#pragma unroll
    for (int j = 0; j < 4; ++j)
      bfr[j] = *(const bf16x8*)(&Bs[(wn + j * 16 + l16) * 32 + quad * 8]);
#pragma unroll
    for (int i = 0; i < MI; ++i)
#pragma unroll
      for (int j = 0; j < 4; ++j)
        acc[i][j] = mfma_bf16(af[i], bfr[j], acc[i][j]);
  }

#pragma unroll
  for (int i = 0; i < MI; ++i)
#pragma unroll
    for (int j = 0; j < 4; ++j) {
      const int nn = n0 + wn + j * 16 + l16;
      const float bv = bias[nn];
      const int mbase = m0 + wm + i * 16 + quad * 4;
      if (MODE == 1) {
#pragma unroll
        for (int r = 0; r < 4; ++r)
          outF[(size_t)(mbase + r) * N + nn] = acc[i][j][r] + bv;
      } else {
        const int which = nn >> 10;  // uniform per block
        const int rem = nn & 1023;
        const int h = rem >> 6, d = rem & 63;
        const int b = mbase >> 11, s = mbase & 2047;
        const size_t bh = (size_t)(b * 16 + h);
        if (which == 2) {
          bf16x4 pk;
#pragma unroll
          for (int r = 0; r < 4; ++r) pk[r] = (bf16)(acc[i][j][r] + bv);
          *(bf16x4*)(vtb + (bh * 64 + d) * 2048 + s) = pk;
        } else if (which == 0) {
#pragma unroll
          for (int r = 0; r < 4; ++r)
            qb[(bh * 2048 + s + r) * 64 + d] = (bf16)((acc[i][j][r] + bv) * SCL);
        } else {
#pragma unroll
          for (int r = 0; r < 4; ++r)
            kb[(bh * 2048 + s + r) * 64 + d] = (bf16)(acc[i][j][r] + bv);
        }
      }
    }
}

// ---- Flash attention, causal. 1024 blocks x 256 threads (4 waves). ------
// Block = one 64-row q-group g of one head. Wave w: strip=(w>>1) (32 rows),
// ms=(w&1) (32-s half of each staged 64-s tile). In-register P via
// pack2+permlane32_swap. Final ms0+ms1 strip merge through dead KV LDS.
__global__ __launch_bounds__(256, 4) void attn_kernel(
    const bf16* __restrict__ Qb, const bf16* __restrict__ Kb,
    const bf16* __restrict__ Vtb, bf16* __restrict__ attnb) {
  __shared__ bf16 Ks[2][4096];  // [buf][64 s-rows x 64 d] swizzled chunks
  __shared__ bf16 Vs[2][4096];  // [buf][64 d-rows x 64 s] swizzled chunks
  const int bid = blockIdx.x;
  const int c = bid & 255, qq = bid >> 8;
  const int bh = c & 31;        // head: all 32 blocks of a head on one XCD
  const int kk = c >> 5;        // 0..7
  // stride-256 columns get groups {k, 31-k, 8+k, 23-k}: 66 iters/column
  const int g = (qq == 0) ? kk : (qq == 1) ? 31 - kk
              : (qq == 2) ? 8 + kk : 23 - kk;
  const int tid = threadIdx.x;
  const int w = tid >> 6, lane = tid & 63;
  const int l31 = lane & 31, hi = lane >> 5;
  const int strip = w >> 1, ms = w & 1;
  const int q0s = g * 64 + strip * 32;  // this wave's 32 q-rows
  const int b = bh >> 4, h = bh & 15;
  const int nt = g + 1;

  const bf16* Qh = Qb + (size_t)bh * 2048 * 64;
  const bf16* Kh = Kb + (size_t)bh * 2048 * 64;
  const bf16* Vh = Vtb + (size_t)bh * 64 * 2048;

  // staging: thread stages chunks {tid, tid+256} of K and of V (16B each).
  // dest chunk c: row=c>>3, slot=c&7 holds source chunk (slot-row)&7
  const int c0 = tid, c1 = tid + 256;
  const int kof0 = (c0 >> 3) * 64 + ((((c0 & 7) - (c0 >> 3)) & 7) * 8);
  const int kof1 = (c1 >> 3) * 64 + ((((c1 & 7) - (c1 >> 3)) & 7) * 8);
  const int vof0 = (c0 >> 3) * 2048 + ((((c0 & 7) - (c0 >> 3)) & 7) * 8);
  const int vof1 = (c1 >> 3) * 2048 + ((((c1 & 7) - (c1 >> 3)) & 7) * 8);

  // Q B-frags: n=q=q0s+l31, k=d=kd*16+hi*8+j
  bf16x8 qf[4];
  {
    const bf16* Qr = Qh + (size_t)(q0s + l31) * 64 + hi * 8;
#pragma unroll
    for (int kd = 0; kd < 4; ++kd) qf[kd] = *(const bf16x8*)(Qr + kd * 16);
  }
  bf16x8 ones;
#pragma unroll
  for (int j = 0; j < 8; ++j) ones[j] = (bf16)1.0f;

  floatx16 O0 = zero16(), O1 = zero16(), Ol = zero16();

  // prologue: stage tile 0 into buffer 0
  cp_g2l_16(Kh + kof0, &Ks[0][c0 * 8]);
  cp_g2l_16(Kh + kof1, &Ks[0][c1 * 8]);
  cp_g2l_16(Vh + vof0, &Vs[0][c0 * 8]);
  cp_g2l_16(Vh + vof1, &Vs[0][c1 * 8]);

  int cur = 0;
  for (int t = 0; t < nt; ++t, cur ^= 1) {
    __syncthreads();  // buf[cur] staged; all waves done with buf[cur^1]
    if (t + 1 < nt) {  // prefetch t+1 into the other buffer
      const int nb = cur ^ 1;
      cp_g2l_16(Kh + (size_t)(t + 1) * 4096 + kof0, &Ks[nb][c0 * 8]);
      cp_g2l_16(Kh + (size_t)(t + 1) * 4096 + kof1, &Ks[nb][c1 * 8]);
      cp_g2l_16(Vh + (size_t)(t + 1) * 64 + vof0, &Vs[nb][c0 * 8]);
      cp_g2l_16(Vh + (size_t)(t + 1) * 64 + vof1, &Vs[nb][c1 * 8]);
    }
    const bool diag = (t == g);
    if (diag && strip == 0 && ms == 1) continue;  // fully-masked half-tile
    const bf16* KsC = Ks[cur];
    const bf16* VsC = Vs[cur];

    // S^T = K*Q^T over this wave's 32 s-rows: 4 chained MFMAs over d
    floatx16 sf = zero16();
    const int row = ms * 32 + l31;
#pragma unroll
    for (int kd = 0; kd < 4; ++kd) {
      bf16x8 kf = *(const bf16x8*)(
          &KsC[row * 64 + (((kd * 2 + hi) + row) & 7) * 8]);
      sf = mfma32(kf, qf[kd], sf);
    }

    // V B-frags for this wave's two 16-s slots (independent of softmax)
    const int ksA = ms * 2, ksB = ms * 2 + 1;
    const int r0 = l31, r1 = 32 + l31;
    bf16x8 va0 = *(const bf16x8*)(&VsC[r0 * 64 + (((ksA * 2 + hi) + r0) & 7) * 8]);
    bf16x8 va1 = *(const bf16x8*)(&VsC[r1 * 64 + (((ksA * 2 + hi) + r1) & 7) * 8]);
    bf16x8 vb0 = *(const bf16x8*)(&VsC[r0 * 64 + (((ksB * 2 + hi) + r0) & 7) * 8]);
    bf16x8 vb1 = *(const bf16x8*)(&VsC[r1 * 64 + (((ksB * 2 + hi) + r1) & 7) * 8]);

    // mask -> exp2
    float e[16];
#pragma unroll
    for (int r = 0; r < 16; ++r) {
      float s = sf[r];
      if (diag) {
        const int kc = t * 64 + ms * 32 + (r & 3) + 8 * (r >> 2) + 4 * hi;
        s = (kc <= q0s + l31) ? s : -1e30f;
      }
      e[r] = __builtin_amdgcn_exp2f(s);
    }

    // in-register P: pack bf16 pairs, swap halves across lane<32/lane>=32
    uint32_t W[8];
#pragma unroll
    for (int i = 0; i < 8; ++i) W[i] = pack2(e[2 * i], e[2 * i + 1]);
    uint2v s0 = permswap(W[0], W[2]);  // ksA: (word0, word2)
    uint2v s1 = permswap(W[1], W[3]);  // ksA: (word1, word3)
    bf16x8 pa = mk_pf(s0.x, s1.x, s0.y, s1.y);
    uint2v s2 = permswap(W[4], W[6]);  // ksB
    uint2v s3 = permswap(W[5], W[7]);
    bf16x8 pb = mk_pf(s2.x, s3.x, s2.y, s3.y);

    // O[q][d] += P V ; l[q] += P * 1
    O0 = mfma32(pa, va0, O0);
    O1 = mfma32(pa, va1, O1);
    Ol = mfma32(pa, ones, Ol);
    O0 = mfma32(pb, vb0, O0);
    O1 = mfma32(pb, vb1, O1);
    Ol = mfma32(pb, ones, Ol);
  }

  // merge ms-halves per strip through dead KV LDS, then write out.
  // fO: [strip][ql 0..31][d 0..63] fp32 = 4096 floats = all of Ks.
  // fL: [strip][ql] = 64 floats at start of Vs.
  __syncthreads();
  float* fO = (float*)(&Ks[0][0]);
  float* fL = (float*)(&Vs[0][0]);
  if (ms == 1) {
#pragma unroll
    for (int r = 0; r < 16; ++r) {
      const int ql = (r & 3) + 8 * (r >> 2) + 4 * hi;
      fO[strip * 2048 + ql * 64 + l31] = O0[r];
      fO[strip * 2048 + ql * 64 + 32 + l31] = O1[r];
      if (l31 == 0) fL[strip * 32 + ql] = Ol[r];
    }
  }
  __syncthreads();
  if (ms == 0) {
#pragma unroll
    for (int r = 0; r < 16; ++r) {
      const int ql = (r & 3) + 8 * (r >> 2) + 4 * hi;
      O0[r] += fO[strip * 2048 + ql * 64 + l31];
      O1[r] += fO[strip * 2048 + ql * 64 + 32 + l31];
      Ol[r] += fL[strip * 32 + ql];
    }
#pragma unroll
    for (int r = 0; r < 16; ++r) {
      const int q = q0s + (r & 3) + 8 * (r >> 2) + 4 * hi;
      const float inv = 1.f / Ol[r];
      bf16* dst = attnb + ((size_t)(b * 2048 + q)) * 1024 + h * 64;
      dst[l31] = (bf16)(O0[r] * inv);
      dst[32 + l31] = (bf16)(O1[r] * inv);
    }
  }
}

// ---------------------------------------------------------------------------
extern "C" void kernel_launch(void* const* d_in, const int* in_sizes, int n_in,
                              void* d_out, int out_size, void* d_ws, size_t ws_size,
                              hipStream_t stream) {
  const float* x     = (const float*)d_in[0];  // (2,2048,1024)
  const float* w_qkv = (const float*)d_in[1];  // (1024,3072)
  const float* b_qkv = (const float*)d_in[2];  // (3072)
  const float* w_o   = (const float*)d_in[3];  // (1024,1024)
  const float* b_o   = (const float*)d_in[4];  // (1024)
  float* out = (float*)d_out;                  // (2,2048,1024) fp32

  char* ws = (char*)d_ws;
  bf16* xb    = (bf16*)ws; ws += (size_t)4096 * 1024 * 2;
  bf16* wqkvt = (bf16*)ws; ws += (size_t)3072 * 1024 * 2;
  bf16* wot   = (bf16*)ws; ws += (size_t)1024 * 1024 * 2;
  bf16* qb    = (bf16*)ws; ws += (size_t)32 * 2048 * 64 * 2;
  bf16* kb    = (bf16*)ws; ws += (size_t)32 * 2048 * 64 * 2;
  bf16* vtb   = (bf16*)ws; ws += (size_t)32 * 2048 * 64 * 2;  // (bh,64,S)
  bf16* attnb = (bf16*)ws; ws += (size_t)4096 * 1024 * 2;

  prep_kernel<<<8192, 256, 0, stream>>>(x, xb, w_qkv, wqkvt, w_o, wot);
  gemm_bt_kernel<0, 4><<<dim3(24, 32), 256, 0, stream>>>(
      xb, wqkvt, b_qkv, nullptr, qb, kb, vtb, 3072, 1024);
  attn_kernel<<<1024, 256, 0, stream>>>(qb, kb, vtb, attnb);
  gemm_bt_kernel<1, 2><<<dim3(8, 64), 256, 0, stream>>>(
      attnb, wot, b_o, out, nullptr, nullptr, nullptr, 1024, 1024);
}